// Round 8
// baseline (254.414 us; speedup 1.0000x reference)
//
#include <hip/hip_runtime.h>
#include <hip/hip_bf16.h>
#include <cstdint>

#define S_LEN   2048
#define DMODEL  1024
#define NHEAD   8
#define HD      128
// SCALE * log2(e): scores computed in exp2 domain
#define QSCALE  (0.08838834764831845f * 1.4426950408889634f)
#define THR2    11.5416f   // defer-max threshold (8 in ln-domain)

typedef __attribute__((ext_vector_type(8))) short  bf16x8;
typedef __attribute__((ext_vector_type(4))) float  f32x4;

typedef __attribute__((address_space(1))) const unsigned int gu32;
typedef __attribute__((address_space(3))) unsigned int       lu32;

static __device__ __forceinline__ unsigned short f2bf(float x) {
  union { float f; unsigned u; } c; c.f = x;
  unsigned u = c.u + 0x7fff + ((c.u >> 16) & 1);
  return (unsigned short)(u >> 16);
}
static __device__ __forceinline__ f32x4 fz4() {
  f32x4 v; v[0] = 0.f; v[1] = 0.f; v[2] = 0.f; v[3] = 0.f; return v;
}

// ---------------------------------------------------------------------------
// x (fp32) -> bf16
// ---------------------------------------------------------------------------
__global__ __launch_bounds__(256) void xcvt_kernel(
    const float* __restrict__ X, unsigned short* __restrict__ Xb)
{
  const int i = blockIdx.x * 256 + threadIdx.x;       // 4 elems each
  const float4 v = ((const float4*)X)[i];
  ushort4 o;
  o.x = f2bf(v.x); o.y = f2bf(v.y); o.z = f2bf(v.z); o.w = f2bf(v.w);
  ((ushort4*)Xb)[i] = o;
}

// ---------------------------------------------------------------------------
// LoRA weight fusion, LDS-tiled: out = bf16(w + (b@a)/64).
// Block = 64 output rows x 128 cols. b-tile [64][64] staged once; a staged in
// [16][128] chunks. ~30 MB total traffic (vs 655 MB naive).
// Concat rows: 0..1023 Wq, 1024..1279 Wk, 1280..1535 Wv, 1536..2559 Wo.
// ---------------------------------------------------------------------------
__global__ __launch_bounds__(256) void fuse_all_kernel(
    const float* __restrict__ wq_w, const float* __restrict__ wq_a, const float* __restrict__ wq_b,
    const float* __restrict__ wk_w, const float* __restrict__ wk_a, const float* __restrict__ wk_b,
    const float* __restrict__ wv_w, const float* __restrict__ wv_a, const float* __restrict__ wv_b,
    const float* __restrict__ wo_w, const float* __restrict__ wo_a, const float* __restrict__ wo_b,
    unsigned short* __restrict__ Wqkv, unsigned short* __restrict__ Wo)
{
  __shared__ float bs[64][65];
  __shared__ float as[16][132];
  const int t  = threadIdx.x;
  const int cb = blockIdx.x & 7, rb = blockIdx.x >> 3;   // 8 col-blocks x 40 row-blocks
  const int o0 = rb * 64;
  const float *w, *a, *b; unsigned short* outp; int ob;
  if (o0 < 1024)      { w = wq_w; a = wq_a; b = wq_b; outp = Wqkv;             ob = o0; }
  else if (o0 < 1280) { w = wk_w; a = wk_a; b = wk_b; outp = Wqkv + 1024*1024; ob = o0 - 1024; }
  else if (o0 < 1536) { w = wv_w; a = wv_a; b = wv_b; outp = Wqkv + 1280*1024; ob = o0 - 1280; }
  else                { w = wo_w; a = wo_a; b = wo_b; outp = Wo;               ob = o0 - 1536; }

#pragma unroll
  for (int i = 0; i < 4; ++i) {                          // stage b[64][64]
    const int rr = (t >> 4) + i * 16, cc = (t & 15) * 4;
    *(float4*)&bs[rr][cc] = *(const float4*)(b + (size_t)(ob + rr) * 64 + cc);
  }

  const int c0 = cb * 128;
  const int tr = t >> 5;                                 // 8 row-groups of 8
  const int co = (t & 31) * 4;                           // col within 128
  float4 ac[8];
#pragma unroll
  for (int i = 0; i < 8; ++i) ac[i] = {0.f, 0.f, 0.f, 0.f};

#pragma unroll 1
  for (int r0 = 0; r0 < 64; r0 += 16) {
    __syncthreads();
#pragma unroll
    for (int i = 0; i < 2; ++i) {                        // stage a[16][128]
      const int rr = (t >> 5) + i * 8, cc = (t & 31) * 4;
      *(float4*)&as[rr][cc] = *(const float4*)(a + (size_t)(r0 + rr) * 1024 + c0 + cc);
    }
    __syncthreads();
#pragma unroll
    for (int rr = 0; rr < 16; ++rr) {
      const float4 av = *(const float4*)&as[rr][co];
#pragma unroll
      for (int ri = 0; ri < 8; ++ri) {
        const float bv = bs[tr * 8 + ri][r0 + rr];
        ac[ri].x += bv * av.x; ac[ri].y += bv * av.y;
        ac[ri].z += bv * av.z; ac[ri].w += bv * av.w;
      }
    }
  }

#pragma unroll
  for (int ri = 0; ri < 8; ++ri) {
    const int row = tr * 8 + ri;
    const float4 wv = *(const float4*)(w + (size_t)(ob + row) * 1024 + c0 + co);
    ushort4 ov;
    ov.x = f2bf(wv.x + ac[ri].x * 0.015625f);
    ov.y = f2bf(wv.y + ac[ri].y * 0.015625f);
    ov.z = f2bf(wv.z + ac[ri].z * 0.015625f);
    ov.w = f2bf(wv.w + ac[ri].w * 0.015625f);
    *(ushort4*)(outp + (size_t)(ob + row) * 1024 + c0 + co) = ov;
  }
}

// ---------------------------------------------------------------------------
// bf16 MFMA GEMM: Y = A @ B^T.  A:[M][K] bf16, B:[N][K] bf16, Y fp32.
// BM=64, BN=64, BK=64. 256 threads = 4 waves; wave tile 32x32.
// LDS double-buffered (32 KB), global_load_lds(16B), XOR-swizzled source.
// HEADMAJOR: Y[(col>>7)*M*128 + row*128 + (col&127)]; else row-major [M][N].
// ---------------------------------------------------------------------------
template<int HEADMAJOR>
__global__ __launch_bounds__(256) void gemm_bf16(
    const unsigned short* __restrict__ A, const unsigned short* __restrict__ B,
    float* __restrict__ Y, int M, int N, int K)
{
  __shared__ __align__(16) unsigned short lds[2][128 * 64];
  const int t = threadIdx.x;
  const int l = t & 63, wid = t >> 6;
  const int lr = l & 15, lq = l >> 4;
  const int m0 = blockIdx.y * 64, n0 = blockIdx.x * 64;
  const int wm = (wid >> 1) * 32, wn = (wid & 1) * 32;

  f32x4 acc[2][2];
#pragma unroll
  for (int i = 0; i < 2; ++i)
#pragma unroll
    for (int j = 0; j < 2; ++j) acc[i][j] = fz4();

  auto stage = [&](int buf, int k0) {
#pragma unroll
    for (int i = 0; i < 4; ++i) {
      const int ch = wid * 4 + i;
      const unsigned short* src;
      unsigned short* dst;
      int row;
      if (ch < 8) {                       // A rows ch*8..+8
        row = ch * 8 + (l >> 3);
        src = A + (size_t)(m0 + row) * K + k0;
        dst = &lds[buf][ch * 512];
      } else {                            // B rows
        row = (ch - 8) * 8 + (l >> 3);
        src = B + (size_t)(n0 + row) * K + k0;
        dst = &lds[buf][ch * 512];
      }
      const int cg = (l & 7) ^ (row & 7); // pre-swizzled source chunk
      __builtin_amdgcn_global_load_lds((gu32*)(src + cg * 8), (lu32*)dst, 16, 0, 0);
    }
  };

  auto compute = [&](int buf) {
    const unsigned short* la = &lds[buf][0];
    const unsigned short* lb = &lds[buf][4096];
    bf16x8 af[2][2], bfr[2][2];
#pragma unroll
    for (int mi = 0; mi < 2; ++mi)
#pragma unroll
      for (int c = 0; c < 2; ++c) {
        const int row = wm + mi * 16 + lr;
        const int ck = (c * 4 + lq) ^ (row & 7);
        af[mi][c] = *(const bf16x8*)(la + row * 64 + ck * 8);
      }
#pragma unroll
    for (int nj = 0; nj < 2; ++nj)
#pragma unroll
      for (int c = 0; c < 2; ++c) {
        const int row = wn + nj * 16 + lr;
        const int ck = (c * 4 + lq) ^ (row & 7);
        bfr[nj][c] = *(const bf16x8*)(lb + row * 64 + ck * 8);
      }
#pragma unroll
    for (int c = 0; c < 2; ++c)
#pragma unroll
      for (int mi = 0; mi < 2; ++mi)
#pragma unroll
        for (int nj = 0; nj < 2; ++nj)
          acc[mi][nj] = __builtin_amdgcn_mfma_f32_16x16x32_bf16(
              af[mi][c], bfr[nj][c], acc[mi][nj], 0, 0, 0);
  };

  const int NT = K >> 6;
  stage(0, 0);
  int cur = 0;
#pragma unroll 1
  for (int kt = 0; kt < NT; ++kt) {
    __syncthreads();                       // drains vmcnt: staged buf[cur] visible
    if (kt + 1 < NT) stage(cur ^ 1, (kt + 1) << 6);
    compute(cur);
    cur ^= 1;
  }

#pragma unroll
  for (int mi = 0; mi < 2; ++mi)
#pragma unroll
    for (int nj = 0; nj < 2; ++nj)
#pragma unroll
      for (int r = 0; r < 4; ++r) {
        const int row = m0 + wm + mi * 16 + lq * 4 + r;
        const int col = n0 + wn + nj * 16 + lr;
        if (HEADMAJOR)
          Y[(((size_t)(col >> 7) * M + row) << 7) + (col & 127)] = acc[mi][nj][r];
        else
          Y[(size_t)row * N + col] = acc[mi][nj][r];
      }
}

// ---------------------------------------------------------------------------
// RoPE + bf16 convert. QKV fp32 [12][2048][128] head-major.
// Sections 0..7 -> Qb (scaled by QSCALE), 8..9 -> Kb.
// ---------------------------------------------------------------------------
__global__ __launch_bounds__(256) void rope_cvt_kernel(
    const float* __restrict__ QKV, const float* __restrict__ fc,
    const int* __restrict__ sp,
    unsigned short* __restrict__ Qb, unsigned short* __restrict__ Kb)
{
  const int idx = blockIdx.x * 256 + threadIdx.x;  // 10*2048*64
  const int i   = idx & 63;
  const int s   = (idx >> 6) & (S_LEN - 1);
  const int sec = idx >> 17;
  const float2 v  = *(const float2*)(QKV + ((size_t)sec * S_LEN + s) * 128 + 2 * i);
  const float2 cs = *(const float2*)(fc + (size_t)(sp[0] + s) * 128 + 2 * i);
  float xr = v.x * cs.x - v.y * cs.y;
  float yr = v.x * cs.y + v.y * cs.x;
  if (sec < 8) { xr *= QSCALE; yr *= QSCALE; }
  const unsigned w = (unsigned)f2bf(xr) | ((unsigned)f2bf(yr) << 16);
  if (sec < 8)
    ((unsigned*)Qb)[(((size_t)sec * S_LEN + s) * 128 + 2 * i) >> 1] = w;
  else
    ((unsigned*)Kb)[(((size_t)(sec - 8) * S_LEN + s) * 128 + 2 * i) >> 1] = w;
}

// ---------------------------------------------------------------------------
// V transpose via LDS tile: QKV sections 10..11 fp32 [s][d] -> Vt bf16 [kh][d][s]
// ---------------------------------------------------------------------------
__global__ __launch_bounds__(256) void vtrans_kernel(
    const float* __restrict__ QKV, unsigned short* __restrict__ Vt)
{
  __shared__ float T[64][68];
  const int t = threadIdx.x;
  const int b = blockIdx.x;           // 2 kh x 32 s-tiles x 2 d-tiles = 128
  const int dt = b & 1, st = (b >> 1) & 31, kh = b >> 6;
  const int s0 = st * 64, d0 = dt * 64;
  const float* src = QKV + ((size_t)(10 + kh) * S_LEN + s0) * 128 + d0;
  const int row = t >> 4, c4 = (t & 15) * 4;
#pragma unroll
  for (int i = 0; i < 4; ++i) {
    const float4 v = *(const float4*)(src + (size_t)(row + i * 16) * 128 + c4);
    *(float4*)&T[row + i * 16][c4] = v;
  }
  __syncthreads();
  const int dl = t >> 2, s4 = (t & 3) * 16;
  unsigned short* dst = Vt + ((size_t)(kh * 128 + d0 + dl)) * S_LEN + s0 + s4;
#pragma unroll
  for (int half = 0; half < 2; ++half) {
    union { unsigned short u[8]; uint4 q; } o;
#pragma unroll
    for (int jj = 0; jj < 8; ++jj) o.u[jj] = f2bf(T[s4 + half * 8 + jj][dl]);
    *(uint4*)(dst + half * 8) = o.q;
  }
}

// ---------------------------------------------------------------------------
// Sparse multi-window attention: 4-wave two-pass split-K.
// Block = 256 threads (4 waves) per (head, 16 q-rows); wave w owns quarter w
// of the tile list. Pass 1: K-prefetched QK^T -> wave-uniform deferred max +
// class sums (no V/P/O). Cross-wave Z combine in LDS -> per-row coefficients
// cA/cB/cC. Pass 2: recompute scores, P' = exp2(s-M*)*coef (coef folded ->
// ONE O accumulator, no mixed-tile double-PV), PV. Cross-wave O sum in LDS.
// Classes: A = key<128 | |d|<=128 ; B = (128,256] ; C = (256,512].
// ---------------------------------------------------------------------------
__global__ __launch_bounds__(256, 3) void attn_kernel(
    const unsigned short* __restrict__ Qb,  // [8][2048][128] pre-scaled
    const unsigned short* __restrict__ Kb,  // [2][2048][128]
    const unsigned short* __restrict__ Vt,  // [2][128][2048]
    const float* __restrict__ swp,          // 3 window weights (pre-softmax)
    unsigned short* __restrict__ AO)        // [2048][1024] bf16
{
  __shared__ __align__(16) unsigned short P[4][512];   // per-wave P tile
  __shared__ float OS[4][32][65];                      // per-wave O partials
  __shared__ float ST[4][3][16];                       // per-wave class sums
  __shared__ float MB[4];                              // per-wave max

  const int t   = threadIdx.x;
  const int wid = t >> 6, l = t & 63;
  const int lr  = l & 15, lq = l >> 4;
  const int h   = blockIdx.y;
  const int q0  = blockIdx.x << 4;
  const int kvh = h >> 2;

  const unsigned short* Kp = Kb + (size_t)kvh * S_LEN * 128;
  const unsigned short* Vp = Vt + (size_t)kvh * 128 * S_LEN;

  bf16x8 qf[4];
#pragma unroll
  for (int c = 0; c < 4; ++c)
    qf[c] = *(const bf16x8*)(Qb + ((size_t)(h * S_LEN + q0 + lr)) * 128 + c * 32 + lq * 8);

  // ---- tile list: [0,4) prefix U [t0w,t1w]; wave takes quarter [jb,je) ----
  const int t0w = (q0 >= 512) ? ((q0 - 512) >> 5) : 0;
  const int t1w = min(63, (q0 + 527) >> 5);
  int nA, base;
  if (t0w < 4) { nA = 0; base = 0; }
  else         { nA = 4; base = t0w; }
  const int n  = nA + t1w - base + 1;
  const int jb = (n * wid) >> 2;
  const int je = (n * (wid + 1)) >> 2;

#define TILE(J) (((J) < nA) ? (J) : (base + (J) - nA))

#define LOADK(DST, K0)                                                         \
  { _Pragma("unroll") for (int c = 0; c < 4; ++c) {                            \
      DST[c]     = *(const bf16x8*)(Kp + (size_t)((K0) + lr) * 128 + c * 32 + lq * 8);      \
      DST[4 + c] = *(const bf16x8*)(Kp + (size_t)((K0) + 16 + lr) * 128 + c * 32 + lq * 8); \
    } }

  float sA[4], sB[4], sC[4];
#pragma unroll
  for (int r = 0; r < 4; ++r) { sA[r] = 0.f; sB[r] = 0.f; sC[r] = 0.f; }
  float M = -1e30f;

  // =============================== PASS 1 ===============================
#define PASS1_TILE(KF)                                                         \
  { const int k0 = tc << 5;                                                    \
    f32x4 s0 = fz4(), s1 = fz4();                                              \
    _Pragma("unroll") for (int c = 0; c < 4; ++c)                              \
      s0 = __builtin_amdgcn_mfma_f32_16x16x32_bf16(qf[c], KF[c], s0, 0, 0, 0); \
    _Pragma("unroll") for (int c = 0; c < 4; ++c)                              \
      s1 = __builtin_amdgcn_mfma_f32_16x16x32_bf16(qf[c], KF[4 + c], s1, 0, 0, 0); \
    const int dminT = k0 - (q0 + 15), dmaxT = k0 + 31 - q0;                    \
    const int aminT = (dminT <= 0 && dmaxT >= 0) ? 0 : min(::abs(dminT), ::abs(dmaxT)); \
    const int amaxT = max(::abs(dminT), ::abs(dmaxT));                         \
    const int bminT = aminT <= 128 ? 0 : aminT <= 256 ? 1 : 2;                 \
    const int bmaxT = amaxT <= 128 ? 0 : amaxT <= 256 ? 1 : amaxT <= 512 ? 2 : 3; \
    const bool unif = (k0 < 128) || (bminT == bmaxT);                          \
    const int  ucls = (k0 < 128) ? 0 : bminT;                                  \
    float lm = fmaxf(fmaxf(s0[0], s1[0]), fmaxf(s0[1], s1[1]));                \
    lm = fmaxf(lm, fmaxf(fmaxf(s0[2], s1[2]), fmaxf(s0[3], s1[3])));           \
    if (__any(lm > M + THR2)) {                                                \
      float wm = lm;                                                           \
      wm = fmaxf(wm, __shfl_xor(wm, 1, 64));  wm = fmaxf(wm, __shfl_xor(wm, 2, 64)); \
      wm = fmaxf(wm, __shfl_xor(wm, 4, 64));  wm = fmaxf(wm, __shfl_xor(wm, 8, 64)); \
      wm = fmaxf(wm, __shfl_xor(wm, 16, 64)); wm = fmaxf(wm, __shfl_xor(wm, 32, 64)); \
      const float Mn = fmaxf(M, wm);                                           \
      const float sc = __builtin_amdgcn_exp2f(M - Mn);                         \
      M = Mn;                                                                  \
      _Pragma("unroll") for (int r = 0; r < 4; ++r) { sA[r] *= sc; sB[r] *= sc; sC[r] *= sc; } \
    }                                                                          \
    _Pragma("unroll") for (int r = 0; r < 4; ++r) {                            \
      float e0 = __builtin_amdgcn_exp2f(s0[r] - M);                            \
      float e1 = __builtin_amdgcn_exp2f(s1[r] - M);                            \
      if (unif) {                                                              \
        if (ucls == 0)      sA[r] += e0 + e1;                                  \
        else if (ucls == 1) sB[r] += e0 + e1;                                  \
        else                sC[r] += e0 + e1;                                  \
      } else {                                                                 \
        const int q  = q0 + lq * 4 + r;                                        \
        const int a0 = ::abs(k0 + lr - q);                                     \
        const int a1 = ::abs(k0 + 16 + lr - q);                                \
        const int c0 = a0 <= 128 ? 0 : a0 <= 256 ? 1 : a0 <= 512 ? 2 : 3;      \
        const int c1 = a1 <= 128 ? 0 : a1 <= 256 ? 1 : a1 <= 512 ? 2 : 3;      \
        if (c0 == 0) sA[r] += e0; else if (c0 == 1) sB[r] += e0; else if (c0 == 2) sC[r] += e0; \
        if (c1 == 0) sA[r] += e1; else if (c1 == 1) sB[r] += e1; else if (c1 == 2) sC[r] += e1; \
      }                                                                        \
    } }

  {
    bf16x8 kA[8], kB[8];
    int j = jb, tc = TILE(jb);
    LOADK(kA, tc << 5);
    for (;;) {
      { const int jn = j + 1; const bool hn = jn < je;
        const int tn = hn ? TILE(jn) : tc;
        if (hn) LOADK(kB, tn << 5);
        PASS1_TILE(kA);
        if (!hn) break;
        j = jn; tc = tn; }
      { const int jn = j + 1; const bool hn = jn < je;
        const int tn = hn ? TILE(jn) : tc;
        if (hn) LOADK(kA, tn << 5);
        PASS1_TILE(kB);
        if (!hn) break;
        j = jn; tc = tn; }
    }
  }

  // reduce class sums over the 16 key-lanes; publish to LDS
#pragma unroll
  for (int r = 0; r < 4; ++r) {
    sA[r] += __shfl_xor(sA[r], 1, 64); sA[r] += __shfl_xor(sA[r], 2, 64);
    sA[r] += __shfl_xor(sA[r], 4, 64); sA[r] += __shfl_xor(sA[r], 8, 64);
    sB[r] += __shfl_xor(sB[r], 1, 64); sB[r] += __shfl_xor(sB[r], 2, 64);
    sB[r] += __shfl_xor(sB[r], 4, 64); sB[r] += __shfl_xor(sB[r], 8, 64);
    sC[r] += __shfl_xor(sC[r], 1, 64); sC[r] += __shfl_xor(sC[r], 2, 64);
    sC[r] += __shfl_xor(sC[r], 4, 64); sC[r] += __shfl_xor(sC[r], 8, 64);
  }
  if (lr == 0) {
#pragma unroll
    for (int r = 0; r < 4; ++r) {
      ST[wid][0][lq * 4 + r] = sA[r];
      ST[wid][1][lq * 4 + r] = sB[r];
      ST[wid][2][lq * 4 + r] = sC[r];
    }
  }
  if (l == 0) MB[wid] = M;
  __syncthreads();

  // ---- combine Z across waves; per-row coefficients ----
  const float Ms = fmaxf(fmaxf(MB[0], MB[1]), fmaxf(MB[2], MB[3]));
  const float fw0 = __builtin_amdgcn_exp2f(MB[0] - Ms);
  const float fw1 = __builtin_amdgcn_exp2f(MB[1] - Ms);
  const float fw2 = __builtin_amdgcn_exp2f(MB[2] - Ms);
  const float fw3 = __builtin_amdgcn_exp2f(MB[3] - Ms);
  const float w0 = swp[0], w1 = swp[1], w2 = swp[2];
  const float mw = fmaxf(w0, fmaxf(w1, w2));
  const float e0 = __expf(w0 - mw), e1 = __expf(w1 - mw), e2 = __expf(w2 - mw);
  const float inv = 1.f / (e0 + e1 + e2);
  const float g0 = e0 * inv, g1 = e1 * inv, g2 = e2 * inv;
  float cfA[4], cfB[4], cfC[4];
#pragma unroll
  for (int r = 0; r < 4; ++r) {
    const int q = lq * 4 + r;
    const float ZA = ST[0][0][q] * fw0 + ST[1][0][q] * fw1 + ST[2][0][q] * fw2 + ST[3][0][q] * fw3;
    const float ZB = ST[0][1][q] * fw0 + ST[1][1][q] * fw1 + ST[2][1][q] * fw2 + ST[3][1][q] * fw3;
    const float ZC = ST[0][2][q] * fw0 + ST[1][2][q] * fw1 + ST[2][2][q] * fw2 + ST[3][2][q] * fw3;
    const float Z1 = ZA, Z2 = Z1 + ZB, Z3 = Z2 + ZC;
    const float cC_ = g2 / Z3;
    const float cB_ = g1 / Z2 + cC_;
    const float cA_ = g0 / Z1 + cB_;
    cfA[r] = cA_; cfB[r] = cB_; cfC[r] = cC_;
  }

  // =============================== PASS 2 ===============================
  f32x4 o[8];
#pragma unroll
  for (int i = 0; i < 8; ++i) o[i] = fz4();

#pragma unroll 1
  for (int j = jb; j < je; ++j) {
    const int tt = TILE(j);
    const int k0 = tt << 5;

    bf16x8 vf0, vf1, vf2, vf3;
    vf0 = *(const bf16x8*)(Vp + (size_t)(0 * 16 + lr) * S_LEN + k0 + lq * 8);
    vf1 = *(const bf16x8*)(Vp + (size_t)(1 * 16 + lr) * S_LEN + k0 + lq * 8);
    vf2 = *(const bf16x8*)(Vp + (size_t)(2 * 16 + lr) * S_LEN + k0 + lq * 8);
    vf3 = *(const bf16x8*)(Vp + (size_t)(3 * 16 + lr) * S_LEN + k0 + lq * 8);

    bf16x8 kA[8];
    LOADK(kA, k0);
    f32x4 s0 = fz4(), s1 = fz4();
#pragma unroll
    for (int c = 0; c < 4; ++c)
      s0 = __builtin_amdgcn_mfma_f32_16x16x32_bf16(qf[c], kA[c], s0, 0, 0, 0);
#pragma unroll
    for (int c = 0; c < 4; ++c)
      s1 = __builtin_amdgcn_mfma_f32_16x16x32_bf16(qf[c], kA[4 + c], s1, 0, 0, 0);

    const int dminT = k0 - (q0 + 15), dmaxT = k0 + 31 - q0;
    const int aminT = (dminT <= 0 && dmaxT >= 0) ? 0 : min(::abs(dminT), ::abs(dmaxT));
    const int amaxT = max(::abs(dminT), ::abs(dmaxT));
    const int bminT = aminT <= 128 ? 0 : aminT <= 256 ? 1 : 2;
    const int bmaxT = amaxT <= 128 ? 0 : amaxT <= 256 ? 1 : amaxT <= 512 ? 2 : 3;
    const bool unif = (k0 < 128) || (bminT == bmaxT);
    const int  ucls = (k0 < 128) ? 0 : bminT;

    float p0[4], p1[4];
#pragma unroll
    for (int r = 0; r < 4; ++r) {
      const float ee0 = __builtin_amdgcn_exp2f(s0[r] - Ms);
      const float ee1 = __builtin_amdgcn_exp2f(s1[r] - Ms);
      float co0, co1;
      if (unif) {
        co0 = (ucls == 0) ? cfA[r] : (ucls == 1) ? cfB[r] : cfC[r];
        co1 = co0;
      } else {
        const int q  = q0 + lq * 4 + r;
        const int a0 = ::abs(k0 + lr - q);
        const int a1 = ::abs(k0 + 16 + lr - q);
        const int c0 = a0 <= 128 ? 0 : a0 <= 256 ? 1 : a0 <= 512 ? 2 : 3;
        const int c1 = a1 <= 128 ? 0 : a1 <= 256 ? 1 : a1 <= 512 ? 2 : 3;
        co0 = (c0 == 0) ? cfA[r] : (c0 == 1) ? cfB[r] : (c0 == 2) ? cfC[r] : 0.f;
        co1 = (c1 == 0) ? cfA[r] : (c1 == 1) ? cfB[r] : (c1 == 2) ? cfC[r] : 0.f;
      }
      p0[r] = ee0 * co0;
      p1[r] = ee1 * co1;
    }

#pragma unroll
    for (int r = 0; r < 4; ++r) {
      const int q = lq * 4 + r;
      P[wid][q * 32 + (((lr >> 3) ^ r) << 3) + (lr & 7)]        = f2bf(p0[r]);
      P[wid][q * 32 + ((((16 + lr) >> 3) ^ r) << 3) + (lr & 7)] = f2bf(p1[r]);
    }
    const bf16x8 pa = *(const bf16x8*)&P[wid][lr * 32 + ((lq ^ (lr & 3)) << 3)];

    o[0] = __builtin_amdgcn_mfma_f32_16x16x32_bf16(pa, vf0, o[0], 0, 0, 0);
    o[1] = __builtin_amdgcn_mfma_f32_16x16x32_bf16(pa, vf1, o[1], 0, 0, 0);
    o[2] = __builtin_amdgcn_mfma_f32_16x16x32_bf16(pa, vf2, o[2], 0, 0, 0);
    o[3] = __builtin_amdgcn_mfma_f32_16x16x32_bf16(pa, vf3, o[3], 0, 0, 0);

    bf16x8 vg0, vg1, vg2, vg3;
    vg0 = *(const bf16x8*)(Vp + (size_t)(4 * 16 + lr) * S_LEN + k0 + lq * 8);
    vg1 = *(const bf16x8*)(Vp + (size_t)(5 * 16 + lr) * S_LEN + k0 + lq * 8);
    vg2 = *(const bf16x8*)(Vp + (size_t)(6 * 16 + lr) * S_LEN + k0 + lq * 8);
    vg3 = *(const bf16x8*)(Vp + (size_t)(7 * 16 + lr) * S_LEN + k0 + lq * 8);
    o[4] = __builtin_amdgcn_mfma_f32_16x16x32_bf16(pa, vg0, o[4], 0, 0, 0);
    o[5] = __builtin_amdgcn_mfma_f32_16x16x32_bf16(pa, vg1, o[5], 0, 0, 0);
    o[6] = __builtin_amdgcn_mfma_f32_16x16x32_bf16(pa, vg2, o[6], 0, 0, 0);
    o[7] = __builtin_amdgcn_mfma_f32_16x16x32_bf16(pa, vg3, o[7], 0, 0, 0);
  }

  // ---- cross-wave O sum + coalesced bf16 store ----
#pragma unroll
  for (int db = 0; db < 8; ++db)
#pragma unroll
    for (int r = 0; r < 4; ++r)
      OS[wid][db * 4 + r][l] = o[db][r];
  __syncthreads();

  const int qr = t >> 4, dc = (t & 15) * 8;
  const int db2 = dc >> 4, dlo = dc & 15;
  const int row = db2 * 4 + (qr & 3);
  const int colb = (qr >> 2) * 16 + dlo;
  union { unsigned short u[8]; uint4 q4; } pk;
#pragma unroll
  for (int jj = 0; jj < 8; ++jj) {
    const float v = OS[0][row][colb + jj] + OS[1][row][colb + jj] +
                    OS[2][row][colb + jj] + OS[3][row][colb + jj];
    pk.u[jj] = f2bf(v);
  }
  *(uint4*)(AO + (size_t)(q0 + qr) * DMODEL + h * HD + dc) = pk.q4;
}

// ---------------------------------------------------------------------------
extern "C" void kernel_launch(void* const* d_in, const int* in_sizes, int n_in,
                              void* d_out, int out_size, void* d_ws, size_t ws_size,
                              hipStream_t stream) {
  const float* x    = (const float*)d_in[0];
  const float* fc   = (const float*)d_in[1];
  const float* wq_w = (const float*)d_in[2];
  const float* wq_a = (const float*)d_in[3];
  const float* wq_b = (const float*)d_in[4];
  const float* wk_w = (const float*)d_in[5];
  const float* wk_a = (const float*)d_in[6];
  const float* wk_b = (const float*)d_in[7];
  const float* wv_w = (const float*)d_in[8];
  const float* wv_a = (const float*)d_in[9];
  const float* wv_b = (const float*)d_in[10];
  const float* wo_w = (const float*)d_in[11];
  const float* wo_a = (const float*)d_in[12];
  const float* wo_b = (const float*)d_in[13];
  const float* sw   = (const float*)d_in[14];
  const int*   sp   = (const int*)d_in[15];
  float* out = (float*)d_out;

  // workspace carve-up (bytes); AO aliases Xbf (dead after QKV GEMM)
  char* wsb = (char*)d_ws;
  unsigned short* Wqkv = (unsigned short*)(wsb + 0);            // 3 MB
  unsigned short* Wo   = (unsigned short*)(wsb + 3145728);      // 2 MB
  unsigned short* Xbf  = (unsigned short*)(wsb + 5242880);      // 4 MB
  float*          QKV  = (float*)(wsb + 9437184);               // 12 MB
  unsigned short* Qb   = (unsigned short*)(wsb + 22020096);     // 4 MB
  unsigned short* Kb   = (unsigned short*)(wsb + 26214400);     // 1 MB
  unsigned short* Vt   = (unsigned short*)(wsb + 27262976);     // 1 MB
  unsigned short* AO   = (unsigned short*)(wsb + 5242880);      // alias Xbf

  // 1. x -> bf16; LoRA fusion (tiled)
  xcvt_kernel<<<2048, 256, 0, stream>>>(x, Xbf);
  fuse_all_kernel<<<320, 256, 0, stream>>>(
      wq_w, wq_a, wq_b, wk_w, wk_a, wk_b, wv_w, wv_a, wv_b, wo_w, wo_a, wo_b,
      Wqkv, Wo);

  // 2. fused QKV projection (N=1536), head-major fp32 output
  gemm_bf16<1><<<dim3(24, 32), 256, 0, stream>>>(Xbf, Wqkv, QKV, 2048, 1536, 1024);

  // 3. RoPE + bf16 (Q scaled); V transpose
  rope_cvt_kernel<<<5120, 256, 0, stream>>>(QKV, fc, sp, Qb, Kb);
  vtrans_kernel<<<128, 256, 0, stream>>>(QKV, Vt);

  // 4. sparse multi-window attention (4-wave two-pass split-K)
  attn_kernel<<<dim3(128, 8), 256, 0, stream>>>(Qb, Kb, Vt, sw, AO);

  // 5. output projection -> fp32 d_out
  gemm_bf16<0><<<dim3(16, 32), 256, 0, stream>>>(AO, Wo, out, 2048, 1024, 1024);
}